// Round 5
// baseline (462.453 us; speedup 1.0000x reference)
//
#include <hip/hip_runtime.h>
#include <math.h>

// ---------- types / helpers ----------
typedef __attribute__((ext_vector_type(8))) short short8;   // 8 bf16 (4 VGPRs)
typedef __attribute__((ext_vector_type(4))) float f32x4;    // MFMA acc

#define MFMA16(a, b, c) __builtin_amdgcn_mfma_f32_16x16x32_bf16((a), (b), (c), 0, 0, 0)

// async global->LDS, 16B per lane. LDS dest is wave-uniform base + lane*16;
// the GLOBAL source address is per-lane -> swizzle the source for free.
__device__ inline void gl_lds16(const void* g, void* l) {
  __builtin_amdgcn_global_load_lds(
      (const __attribute__((address_space(1))) void*)g,
      (__attribute__((address_space(3))) void*)l, 16, 0, 0);
}

__device__ inline unsigned int pack2(float lo, float hi) {
  unsigned int ulo = __float_as_uint(lo), uhi = __float_as_uint(hi);
  return (uhi & 0xFFFF0000u) | (ulo >> 16);
}
__device__ inline unsigned short f2bf_r(float f) {
  return (unsigned short)((__float_as_uint(f) + 0x8000u) >> 16);
}
__device__ inline float bf2f(unsigned short h) {
  return __uint_as_float(((unsigned int)h) << 16);
}

// ---------- K0: merged weight repack ----------
// blocks 0..95:   W1 [3,2048,128] f32 -> W1bt [384,2048] bf16 (B^T, k-contiguous)
// blocks 96..287: W2 [3,128,128] f32  -> W2t  [j][d][c]  bf16 (transposed)
__global__ __launch_bounds__(256) void k_repack(const float* __restrict__ W1,
                                                const float* __restrict__ W2,
                                                unsigned short* __restrict__ W1bt,
                                                unsigned short* __restrict__ W2t) {
  __shared__ float tile[64 * 128];   // 32 KB
  const int b = blockIdx.x, tid = threadIdx.x;
  if (b < 96) {
    const int k = b >> 5, et = b & 31;
    const int e0 = et * 64;
    const float* src = W1 + (size_t)k * 262144 + (size_t)e0 * 128;
#pragma unroll
    for (int i = 0; i < 8; ++i) {
      int idx4 = tid + i * 256;
      ((f32x4*)tile)[idx4] = ((const f32x4*)src)[idx4];
    }
    __syncthreads();
#pragma unroll
    for (int i = 0; i < 4; ++i) {
      int item = tid + i * 256;
      int c = item >> 3, eo = (item & 7) * 8;
      union { unsigned short h[8]; uint4 v; } t;
#pragma unroll
      for (int u = 0; u < 8; ++u) t.h[u] = f2bf_r(tile[(eo + u) * 128 + c]);
      *(uint4*)(W1bt + (size_t)(k * 128 + c) * 2048 + e0 + eo) = t.v;
    }
  } else {
    int idx = (b - 96) * 256 + tid;                 // 49152
    int j = idx >> 14, r = idx & 16383, d = r >> 7, c = r & 127;
    W2t[idx] = f2bf_r(W2[(size_t)j * 16384 + (size_t)c * 128 + d]);
  }
}

// ---------- K1: Ybf[N,384] = X[N,2048] @ W1bt^T ----------
// BM=128 x BN=384 x BK=64, 512 threads (8 waves: 2 row-grp x 4 col-grp, rt=4 exact).
// Double-buffered LDS (A bf16 16KB x2, B bf16 48KB x2 = 128KB), 1 block/CU,
// one barrier per K-iter: stage(k+1)->buf^1 issued BEFORE compute(k) so the
// vmcnt(0) drain at the barrier lands after ~2000 cyc of compute (latency hidden).
__global__ __launch_bounds__(512, 2) void k_gemm1(const float* __restrict__ X,
                                                  const unsigned short* __restrict__ Bt,
                                                  unsigned short* __restrict__ Ybf) {
  __shared__ __align__(16) unsigned short Albuf[2][128 * 64];  // row stride 64 sh (8 chunks of 8), chunk c at slot c^(row&7)
  __shared__ __align__(16) unsigned short Blbuf[2][384 * 64];  // col stride 64 sh, chunk c at slot c^(col&7)

  const int r0 = blockIdx.x * 128;
  const int tid = threadIdx.x, wave = tid >> 6, lane = tid & 63;
  const int mrow = lane & 15, quad = lane >> 4;
  const int rg = wave >> 2, cg = wave & 3;

  // --- B staging source (gl_lds, swizzled): 6 calls/wave, 8 cols each ---
  const unsigned short* bsrc[6];
#pragma unroll
  for (int r = 0; r < 6; ++r) {
    int col = wave * 48 + r * 8 + (lane >> 3);
    int c = (lane & 7) ^ (col & 7);
    bsrc[r] = Bt + (size_t)col * 2048 + c * 8;
  }
  // --- A staging (manual f32->bf16 pack + ds_write_b128): 16 rows/wave ---
  const int arow = wave * 16 + (lane >> 2);
  const float* asrc = X + (size_t)(r0 + arow) * 2048 + (lane & 3) * 16;
  const int ac0 = (lane & 3) * 2;
  const int aslot0 = ac0 ^ (arow & 7), aslot1 = (ac0 + 1) ^ (arow & 7);

  f32x4 acc[4][6] = {};

  auto stageB = [&](unsigned short* Bb, int k0) {
#pragma unroll
    for (int r = 0; r < 6; ++r)
      gl_lds16(bsrc[r] + k0, (char*)Bb + (wave * 48 + r * 8) * 128);
  };
  auto stageA = [&](unsigned short* Ab, int k0) {
    const float* s = asrc + k0;
    f32x4 v0 = *(const f32x4*)(s);
    f32x4 v1 = *(const f32x4*)(s + 4);
    f32x4 v2 = *(const f32x4*)(s + 8);
    f32x4 v3 = *(const f32x4*)(s + 12);
    union { unsigned int u[4]; short8 h; } t0, t1;
    t0.u[0] = pack2(v0[0], v0[1]); t0.u[1] = pack2(v0[2], v0[3]);
    t0.u[2] = pack2(v1[0], v1[1]); t0.u[3] = pack2(v1[2], v1[3]);
    t1.u[0] = pack2(v2[0], v2[1]); t1.u[1] = pack2(v2[2], v2[3]);
    t1.u[2] = pack2(v3[0], v3[1]); t1.u[3] = pack2(v3[2], v3[3]);
    *(short8*)(Ab + arow * 64 + aslot0 * 8) = t0.h;
    *(short8*)(Ab + arow * 64 + aslot1 * 8) = t1.h;
  };
  auto compute = [&](const unsigned short* Ab, const unsigned short* Bb) {
#pragma unroll
    for (int s = 0; s < 2; ++s) {
      const int ch = (s * 4 + quad) ^ (mrow & 7);   // row&7 == col&7 == mrow&7
      short8 af[4];
#pragma unroll
      for (int rt = 0; rt < 4; ++rt)
        af[rt] = *(const short8*)(Ab + (rg * 64 + rt * 16 + mrow) * 64 + ch * 8);
#pragma unroll
      for (int ct = 0; ct < 6; ++ct) {
        short8 bf = *(const short8*)(Bb + (cg * 96 + ct * 16 + mrow) * 64 + ch * 8);
#pragma unroll
        for (int rt = 0; rt < 4; ++rt)
          acc[rt][ct] = MFMA16(af[rt], bf, acc[rt][ct]);
      }
    }
  };

  // prologue: stage k=0 into buf0
  stageB(Blbuf[0], 0);
  stageA(Albuf[0], 0);
  __syncthreads();

  for (int ii = 0; ii < 16; ++ii) {
    const int k0 = ii * 128;
    // even phase: stage k0+64 -> buf1, compute buf0
    stageB(Blbuf[1], k0 + 64);
    stageA(Albuf[1], k0 + 64);
    compute(Albuf[0], Blbuf[0]);
    __syncthreads();
    // odd phase: stage k0+128 -> buf0 (skip on last), compute buf1
    if (k0 + 128 < 2048) {
      stageB(Blbuf[0], k0 + 128);
      stageA(Albuf[0], k0 + 128);
    }
    compute(Albuf[1], Blbuf[1]);
    __syncthreads();
  }

  // epilogue: C layout col=lane&15, row=quad*4+reg (verified R1-R4)
#pragma unroll
  for (int rt = 0; rt < 4; ++rt)
#pragma unroll
    for (int ct = 0; ct < 6; ++ct)
#pragma unroll
      for (int g = 0; g < 4; ++g) {
        int row = r0 + rg * 64 + rt * 16 + quad * 4 + g;
        int col = cg * 96 + ct * 16 + mrow;
        Ybf[(size_t)row * 384 + col] = f2bf_r(acc[rt][ct][g]);
      }
}

// ---------- K2: tap-sum + tanh -> H (LDS bf16), 3 shifted GEMMs vs W2, log-softmax ----------
#define HS 136  // 128 + 8 pad
__global__ __launch_bounds__(256) void k_stage2(const unsigned short* __restrict__ Yb,
                                                const unsigned short* __restrict__ W2t,
                                                const float* __restrict__ b1,
                                                const float* __restrict__ b2,
                                                float* __restrict__ out) {
  __shared__ unsigned short Hlds[66 * HS];  // rows r0-2 .. r0+63
  __shared__ float zbuf[2][128];
  const int bid = blockIdx.x, tid = threadIdx.x;
  const int r0 = bid * 64;

  // H[p] = tanh( Y[p][c] + Y[p-1][128+c] + Y[p-2][256+c] + cnt*b1[c] )
  for (int idx = tid; idx < 66 * 128; idx += 256) {
    int hl = idx >> 7, c = idx & 127;
    int p = r0 - 2 + hl;
    float h = 0.f;
    if (p >= 0) {
      float s = bf2f(Yb[(size_t)p * 384 + c]);
      float cnt = 1.f;
      if (p >= 1) { s += bf2f(Yb[(size_t)(p - 1) * 384 + 128 + c]); cnt += 1.f; }
      if (p >= 2) { s += bf2f(Yb[(size_t)(p - 2) * 384 + 256 + c]); cnt += 1.f; }
      h = tanhf(fmaf(cnt, b1[c], s));
    }
    Hlds[hl * HS + c] = f2bf_r(h);
  }
  __syncthreads();

  const int wave = tid >> 6, lane = tid & 63, mrow = lane & 15, quad = lane >> 4;
  f32x4 acc[8] = {};  // wave: 16 rows x 128 cols (8 ct tiles)
#pragma unroll
  for (int j = 0; j < 3; ++j) {
#pragma unroll
    for (int kk = 0; kk < 4; ++kk) {
      short8 a0 = *(const short8*)&Hlds[(wave * 16 + mrow + j) * HS + kk * 32 + quad * 8];
      const unsigned short* wp = W2t + (size_t)(j * 128 + mrow) * 128 + kk * 32 + quad * 8;
#pragma unroll
      for (int ct = 0; ct < 8; ++ct)
        acc[ct] = MFMA16(a0, *(const short8*)(wp + ct * 16 * 128), acc[ct]);
    }
  }

  // log-softmax per row; row's 128 cols live in 16 lanes (mrow) x 8 ct-regs
#pragma unroll
  for (int rg2 = 0; rg2 < 4; ++rg2) {
    float z[8]; float m = -1e30f;
#pragma unroll
    for (int ct = 0; ct < 8; ++ct) {
      z[ct] = acc[ct][rg2] + 3.f * b2[ct * 16 + mrow];
      m = fmaxf(m, z[ct]);
    }
#pragma unroll
    for (int off = 1; off < 16; off <<= 1) m = fmaxf(m, __shfl_xor(m, off, 64));
    float s = 0.f;
#pragma unroll
    for (int ct = 0; ct < 8; ++ct) s += __expf(z[ct] - m);
#pragma unroll
    for (int off = 1; off < 16; off <<= 1) s += __shfl_xor(s, off, 64);
    float lse = m + __logf(s);
    int grow = r0 + wave * 16 + quad * 4 + rg2;
    if (grow >= 2) {
      float* op = out + (size_t)grow * 128 + mrow;
#pragma unroll
      for (int ct = 0; ct < 8; ++ct) op[ct * 16] = z[ct] - lse;
    }
  }

  // fallback rows 0,1: Z0 = tanh(x@W1[0]+b1) @ W2[0] + b2, then log-softmax
  if (bid == 0) {
    __syncthreads();
    int row = tid >> 7, d = tid & 127;
    zbuf[row][d] = tanhf(bf2f(Yb[(size_t)row * 384 + d]) + b1[d]);
    __syncthreads();
    float zv = b2[d];
    for (int c = 0; c < 128; ++c)
      zv = fmaf(zbuf[row][c], bf2f(W2t[(size_t)d * 128 + c]), zv);  // W2t[0][d][c] = W2[0][c][d]
    __syncthreads();
    zbuf[row][d] = zv;
    __syncthreads();
    float m = -1e30f;
    for (int c = 0; c < 128; ++c) m = fmaxf(m, zbuf[row][c]);
    float s = 0.f;
    for (int c = 0; c < 128; ++c) s += __expf(zbuf[row][c] - m);
    out[(size_t)row * 128 + d] = zv - m - __logf(s);
  }
}

// ---------- launch ----------
extern "C" void kernel_launch(void* const* d_in, const int* in_sizes, int n_in,
                              void* d_out, int out_size, void* d_ws, size_t ws_size,
                              hipStream_t stream) {
  const float* X  = (const float*)d_in[0];   // [32768, 1, 2048]
  const float* W1 = (const float*)d_in[1];   // [3, 2048, 128]
  const float* b1 = (const float*)d_in[2];   // [1, 128]
  const float* W2 = (const float*)d_in[3];   // [3, 128, 128]
  const float* b2 = (const float*)d_in[4];   // [1, 128]
  float* out = (float*)d_out;                // [32768, 1, 128] fp32

  // workspace layout (~27 MB)
  unsigned short* Ybf  = (unsigned short*)d_ws;                           // 32768*384*2 = 25,165,824
  unsigned short* W1bt = (unsigned short*)((char*)d_ws + 25165824);       // 1,572,864
  unsigned short* W2t  = (unsigned short*)((char*)d_ws + 25165824 + 1572864); // 98,304

  k_repack<<<288, 256, 0, stream>>>(W1, W2, W1bt, W2t);
  k_gemm1<<<256, 512, 0, stream>>>(X, W1bt, Ybf);
  k_stage2<<<512, 256, 0, stream>>>(Ybf, W2t, b1, b2, out);
}